// Round 5
// baseline (299.838 us; speedup 1.0000x reference)
//
#include <hip/hip_runtime.h>
#include <math.h>

#define BB 64
#define FF 128
#define TT 4096
#define KK 13
#define NT (BB * TT)          // 262144 columns per tensor (= mcd sample count)
#define MCD_C  6.14185100f    // (10/ln10)*sqrt(2)

// Scales: CMVN divides per-k by std, so ln2 (log1p vs log2) and the DCT
// orthonormal scales cancel exactly (verified absmax 0.0 in round 4).
// Symmetry: b_k(127-f) = cos(k*(pi - theta_f)) = (-1)^k b_k(f) -> process
// f-pairs (f, 127-f): even k accumulate (x1+x2), odd k accumulate (x1-x2).
// One Chebyshev basis per pair => 2-col amortization with only 13 live accs.

// ws layout (bytes):
//   [0,    4096)  : 52 stat accumulators, each on its own 64B line
//   [4096, 8192)  : 1024 per-block mcd partials (pass2 -> pass3)
//   [8192, ...)   : cT planes (13*NT floats), then cP planes (13*NT floats)

#define KLIST(X) X(0) X(1) X(2) X(3) X(4) X(5) X(6) X(7) X(8) X(9) X(10) X(11) X(12)

// Pass 1: 2048 blocks (8/CU, one full round at 8 waves/SIMD); [0,1024)
// stream melT, [1024,2048) stream melP. Thread = ONE t-column: 13 live
// accumulators leave register slack so 16 batched loads stay in flight
// (rounds 1-4: 26 accs ate the budget -> loads serialized -> 107us floor).
__global__ __launch_bounds__(256)
__attribute__((amdgpu_waves_per_eu(8)))
void pass1_kernel(
    const float* __restrict__ melT, const float* __restrict__ melP,
    float* __restrict__ sums, float* __restrict__ cT, float* __restrict__ cP)
{
    const int tensor = blockIdx.x >> 10;                       // 0=true 1=pred
    const int g = ((blockIdx.x & 1023) << 8) + threadIdx.x;    // [0, NT)
    const float* __restrict__ src = tensor ? melP : melT;
    float* __restrict__ dst = tensor ? cP : cT;

    const int b = g >> 12;          // / TT
    const int t = g & (TT - 1);
    const float* p = src + (size_t)b * (FF * TT) + t;

#define DECLACC(i) float a##i = 0.f;
    KLIST(DECLACC)
#undef DECLACC

    for (int f0 = 0; f0 < FF / 2; f0 += 8) {
        // 16 independent dword loads (two coalesced 256B runs per wave)
        float xa[8], xb[8];
#pragma unroll
        for (int j = 0; j < 8; ++j)
            xa[j] = p[(size_t)(f0 + j) * TT];
#pragma unroll
        for (int j = 0; j < 8; ++j)
            xb[j] = p[(size_t)(FF - 1 - f0 - j) * TT];

#pragma unroll
        for (int j = 0; j < 8; ++j) {
            const float x1 = __log2f(1.0f + fabsf(xa[j]));
            const float x2 = __log2f(1.0f + fabsf(xb[j]));
            const float s = x1 + x2;
            const float d = x1 - x2;
            const float c1 = __cosf((3.14159265358979f / 128.0f) *
                                    ((float)(f0 + j) + 0.5f));
            const float tw = c1 + c1;
            float bp = 1.0f, bc = c1;
            a0 += s;
            // rolling Chebyshev: after each use, b_{k+1} = tw*b_k - b_{k-1}
#define ROLL { const float bn = fmaf(tw, bc, -bp); bp = bc; bc = bn; }
            a1  = fmaf(bc, d, a1);  ROLL
            a2  = fmaf(bc, s, a2);  ROLL
            a3  = fmaf(bc, d, a3);  ROLL
            a4  = fmaf(bc, s, a4);  ROLL
            a5  = fmaf(bc, d, a5);  ROLL
            a6  = fmaf(bc, s, a6);  ROLL
            a7  = fmaf(bc, d, a7);  ROLL
            a8  = fmaf(bc, s, a8);  ROLL
            a9  = fmaf(bc, d, a9);  ROLL
            a10 = fmaf(bc, s, a10); ROLL
            a11 = fmaf(bc, d, a11); ROLL
            a12 = fmaf(bc, s, a12);
#undef ROLL
        }
    }

    // cache (unscaled) cepstra: plane k, dword per thread, coalesced
#define STK(i) dst[(size_t)(i) * NT + g] = a##i;
    KLIST(STK)
#undef STK

    // per-k sum & sumsq -> wave shuffle -> LDS(4 waves) -> padded atomics
    __shared__ float red[4][26];
    const int lane = threadIdx.x & 63;
    const int wave = threadIdx.x >> 6;
#define REDK(i) { \
        float s = a##i; \
        float q = a##i * a##i; \
        for (int o = 32; o > 0; o >>= 1) { \
            s += __shfl_down(s, o); q += __shfl_down(q, o); } \
        if (lane == 0) { red[wave][i] = s; red[wave][13 + i] = q; } }
    KLIST(REDK)
#undef REDK
    __syncthreads();
    if (threadIdx.x < 26) {
        const float v = red[0][threadIdx.x] + red[1][threadIdx.x] +
                        red[2][threadIdx.x] + red[3][threadIdx.x];
        atomicAdd(&sums[(tensor * 26 + threadIdx.x) * 16], v);  // own 64B line
    }
}

// Pass 2: finalize mean / 1/(std+1e-6) (ddof=1) in LDS, stream cached
// cepstra (27 MB, LLC-hot), per-column mcd, block partial -> plain store.
// 1 column/thread: 26 independent low-pressure loads stay in flight.
__global__ __launch_bounds__(256) void pass2_kernel(
    const float* __restrict__ sums, const float* __restrict__ cT,
    const float* __restrict__ cP, float* __restrict__ partials)
{
    __shared__ float mT[13], iT[13], mP[13], iP[13];
    if (threadIdx.x < 26) {
        const int tns = threadIdx.x >= 13;
        const int k   = threadIdx.x - tns * 13;
        const float s = sums[(tns * 26 + k) * 16];
        const float q = sums[(tns * 26 + 13 + k) * 16];
        const float N = (float)NT;
        const float m = s / N;
        const float var = fmaxf((q - s * m) / (N - 1.0f), 0.0f);
        const float isd = 1.0f / (sqrtf(var) + 1e-6f);
        if (tns == 0) { mT[k] = m; iT[k] = isd; }
        else          { mP[k] = m; iP[k] = isd; }
    }
    __syncthreads();

    const int g = blockIdx.x * 256 + threadIdx.x;   // [0, NT)
    float vT[KK], vP[KK];
#pragma unroll
    for (int k = 0; k < KK; ++k) vT[k] = cT[(size_t)k * NT + g];
#pragma unroll
    for (int k = 0; k < KK; ++k) vP[k] = cP[(size_t)k * NT + g];

    float ss = 0.0f;
#pragma unroll
    for (int k = 0; k < KK; ++k) {
        const float d = (vT[k] - mT[k]) * iT[k] - (vP[k] - mP[k]) * iP[k];
        ss = fmaf(d, d, ss);
    }
    float v = MCD_C * sqrtf(ss);

    const int lane = threadIdx.x & 63;
    const int wave = threadIdx.x >> 6;
    for (int o = 32; o > 0; o >>= 1) v += __shfl_down(v, o);
    __shared__ float r2[4];
    if (lane == 0) r2[wave] = v;
    __syncthreads();
    if (threadIdx.x == 0)
        partials[blockIdx.x] = r2[0] + r2[1] + r2[2] + r2[3];
}

// Pass 3: one block reduces the 1024 partials and writes the mean.
__global__ __launch_bounds__(256) void pass3_kernel(
    const float* __restrict__ partials, float* __restrict__ out)
{
    float v = partials[threadIdx.x] + partials[threadIdx.x + 256] +
              partials[threadIdx.x + 512] + partials[threadIdx.x + 768];
    const int lane = threadIdx.x & 63;
    const int wave = threadIdx.x >> 6;
    for (int o = 32; o > 0; o >>= 1) v += __shfl_down(v, o);
    __shared__ float r2[4];
    if (lane == 0) r2[wave] = v;
    __syncthreads();
    if (threadIdx.x == 0)
        out[0] = (r2[0] + r2[1] + r2[2] + r2[3]) * (1.0f / (float)NT);
}

extern "C" void kernel_launch(void* const* d_in, const int* in_sizes, int n_in,
                              void* d_out, int out_size, void* d_ws, size_t ws_size,
                              hipStream_t stream) {
    const float* melT = (const float*)d_in[0];
    const float* melP = (const float*)d_in[1];
    float* out      = (float*)d_out;
    float* sums     = (float*)d_ws;                     // padded stats
    float* partials = (float*)((char*)d_ws + 4096);     // 1024 floats
    float* cT       = (float*)((char*)d_ws + 8192);     // 13*NT floats
    float* cP       = cT + (size_t)KK * NT;             // 13*NT floats

    hipMemsetAsync(d_ws, 0, 8192, stream);              // zero stats + partials

    pass1_kernel<<<2048, 256, 0, stream>>>(melT, melP, sums, cT, cP);
    pass2_kernel<<<1024, 256, 0, stream>>>(sums, cT, cP, partials);
    pass3_kernel<<<1, 256, 0, stream>>>(partials, out);
}